// Round 1
// 658.096 us; speedup vs baseline: 1.0634x; 1.0634x over previous
//
#include <hip/hip_runtime.h>
#include <stdint.h>

using bf16x8 = __attribute__((ext_vector_type(8))) short;
using f32x4  = __attribute__((ext_vector_type(4))) float;

__device__ __forceinline__ short f2bf(float f) {
  uint32_t u = __float_as_uint(f);
  u += 0x7fff + ((u >> 16) & 1u);
  return (short)(u >> 16);
}

#define MFMA16(a, b, c) __builtin_amdgcn_mfma_f32_16x16x32_bf16((a), (b), (c), 0, 0, 0)

// async global->LDS, 16B per lane; LDS dest is wave-uniform base + lane*16
__device__ __forceinline__ void gl_lds16(const short* g, short* l) {
  __builtin_amdgcn_global_load_lds(
      (const __attribute__((address_space(1))) void*)g,
      (__attribute__((address_space(3))) void*)l, 16, 0, 0);
}

// ---------------------------------------------------------------------------
// prep_w: pack Wq*scale|Wk|Wv -> bf16 [1152][384], Wp -> bf16, biases fp32
// ---------------------------------------------------------------------------
__global__ void prep_w(const float* __restrict__ Wq, const float* __restrict__ bq,
                       const float* __restrict__ Wk, const float* __restrict__ bk,
                       const float* __restrict__ Wv, const float* __restrict__ bv,
                       const float* __restrict__ Wp, const float* __restrict__ bp,
                       short* __restrict__ Wqkv, short* __restrict__ Wpb,
                       float* __restrict__ bqkv, float* __restrict__ bpb) {
  int i = blockIdx.x * 256 + threadIdx.x;
  const float scale = 0.17677669529663687f;  // 32^-0.5, folded into q
  if (i < 1152 * 384) {
    int r = i / 384, k = i - r * 384;
    float v;
    if (r < 384)      v = Wq[r * 384 + k] * scale;
    else if (r < 768) v = Wk[(r - 384) * 384 + k];
    else              v = Wv[(r - 768) * 384 + k];
    Wqkv[i] = f2bf(v);
  }
  if (i < 384 * 384) Wpb[i] = f2bf(Wp[i]);
  if (i < 1152) bqkv[i] = (i < 384) ? bq[i] * scale : ((i < 768) ? bk[i - 384] : bv[i - 768]);
  if (i < 384) bpb[i] = bp[i];
}

// ---------------------------------------------------------------------------
// prep_bm: bm[wm][h][i][j] = table[relidx(i,j)][h] + mask[wm][i][j]  (fp32)
// ---------------------------------------------------------------------------
__global__ void prep_bm(const float* __restrict__ table, const float* __restrict__ mask,
                        float* __restrict__ bm, int nwmask) {
  int wm = blockIdx.x / 12, h = blockIdx.x - wm * 12;
  const float* mrow = mask + (size_t)wm * 2401;
  float* dst = bm + (size_t)blockIdx.x * 2401;
  for (int e = threadIdx.x; e < 2401; e += 256) {
    int i = e / 49, j = e - i * 49;
    int id = i / 7, ir = i - id * 7;
    int jd = j / 7, jr = j - jd * 7;
    int idx = (id - jd + 6) * 13 + (ir - jr + 6);
    dst[e] = table[idx * 12 + h] + mrow[e];
  }
}

// ---------------------------------------------------------------------------
// prep_x: fp32 -> bf16 conversion of a chunk of x (8 elements / thread)
// ---------------------------------------------------------------------------
__global__ void prep_x(const float* __restrict__ x, short* __restrict__ xb, int n8) {
  int u = blockIdx.x * 256 + threadIdx.x;
  if (u < n8) {
    int e = u * 8;
    float4 f0 = *(const float4*)(x + e);
    float4 f1 = *(const float4*)(x + e + 4);
    bf16x8 cv;
    cv[0] = f2bf(f0.x); cv[1] = f2bf(f0.y); cv[2] = f2bf(f0.z); cv[3] = f2bf(f0.w);
    cv[4] = f2bf(f1.x); cv[5] = f2bf(f1.y); cv[6] = f2bf(f1.z); cv[7] = f2bf(f1.w);
    *(bf16x8*)(xb + e) = cv;
  }
}

// ---------------------------------------------------------------------------
// K1: qkv = xb @ Wqkv.T + bqkv ; writes q,k,v bf16 in [bw][h][n][32] layout
// tile 128(M) x 192(N), 4 waves, BK=64, K=384 (6 iters)
// global_load_lds width-16 staging; linear LDS dest + XOR-swizzled source;
// ds_read side applies the same XOR -> ~2-way (free) bank pattern.
// Block swizzle: ids within a 48-group share id%8 (XCD) and one M-row, so
// the 6 N-blocks re-read the A-tile from the same private L2.
// ---------------------------------------------------------------------------
__global__ __launch_bounds__(256) void qkv_gemm(
    const short* __restrict__ xb, const short* __restrict__ Wqkv,
    const float* __restrict__ bqkv,
    short* __restrict__ qws, short* __restrict__ kws, short* __restrict__ vws,
    int ntok) {
  __shared__ __align__(16) short smem[(128 + 192) * 64];  // As[128][64] | Bs[192][64]
  short* Asl = smem;
  short* Bsl = smem + 128 * 64;
  const int tid = threadIdx.x;
  const int lane = tid & 63, wv = tid >> 6;
  const int c = lane & 15, g = lane >> 4;

  // ---- block swizzle: id -> (xq, yq), 8 rows x 6 cols per 48-id group ----
  const int mt = gridDim.y;
  int id = blockIdx.y * 6 + blockIdx.x;
  int mt8 = mt & ~7;
  int xq, yq;
  if (id < 6 * mt8) {
    int q = id / 48, r = id - q * 48;
    yq = q * 8 + (r & 7);
    xq = r >> 3;
  } else {
    int rem = id - 6 * mt8;
    xq = rem % 6;
    yq = mt8 + rem / 6;
  }
  const int n0 = xq * 192;
  const int row0 = yq * 128;

  f32x4 acc[8][3];
  const f32x4 zero = {0.f, 0.f, 0.f, 0.f};
#pragma unroll
  for (int m = 0; m < 8; m++)
#pragma unroll
    for (int nn = 0; nn < 3; nn++) acc[m][nn] = zero;

  // per-lane source swizzle: lane covers (row r0+(lane>>3), chunk lane&7);
  // logical chunk = (lane&7) ^ (r&7) with r&7 == lane>>3
  const int rsub = lane >> 3;
  const int chnk = ((lane & 7) ^ rsub) * 8;  // short offset within a 64-elt row
  const short* aS[4];
  const short* bS[6];
#pragma unroll
  for (int i = 0; i < 4; i++) {
    int r = (wv * 4 + i) * 8 + rsub;
    int grow = row0 + r;
    if (grow >= ntok) grow = ntok - 1;
    aS[i] = xb + (size_t)grow * 384 + chnk;
  }
#pragma unroll
  for (int j = 0; j < 6; j++) {
    int r = (wv * 6 + j) * 8 + rsub;
    bS[j] = Wqkv + (size_t)(n0 + r) * 384 + chnk;
  }

  for (int ks = 0; ks < 6; ks++) {
    __syncthreads();  // previous tile's ds_reads done before overwrite
#pragma unroll
    for (int i = 0; i < 4; i++)
      gl_lds16(aS[i] + ks * 64, Asl + (wv * 4 + i) * 512);
#pragma unroll
    for (int j = 0; j < 6; j++)
      gl_lds16(bS[j] + ks * 64, Bsl + (wv * 6 + j) * 512);
    __syncthreads();  // drains vmcnt -> tile visible to all waves
#pragma unroll
    for (int kk = 0; kk < 2; kk++) {
      bf16x8 af[8];
#pragma unroll
      for (int m = 0; m < 8; m++) {
        int row = m * 16 + c;
        af[m] = *(const bf16x8*)&Asl[row * 64 + (((kk * 4 + g) ^ (row & 7)) * 8)];
      }
#pragma unroll
      for (int nn = 0; nn < 3; nn++) {
        int row = wv * 48 + nn * 16 + c;
        bf16x8 bfr = *(const bf16x8*)&Bsl[row * 64 + (((kk * 4 + g) ^ (row & 7)) * 8)];
#pragma unroll
        for (int m = 0; m < 8; m++) acc[m][nn] = MFMA16(af[m], bfr, acc[m][nn]);
      }
    }
  }

  // epilogue in two 64-row halves through LDS, scatter to [bw][h][n][32]
  const int s = n0 / 384;
  short* base = (s == 0) ? qws : ((s == 1) ? kws : vws);
  const int hbase = (n0 - s * 384) >> 5;
#pragma unroll
  for (int half = 0; half < 2; half++) {
    __syncthreads();
#pragma unroll
    for (int nn = 0; nn < 3; nn++) {
      int colRel = wv * 48 + nn * 16 + c;
      float bias = bqkv[n0 + colRel];
#pragma unroll
      for (int mm = 0; mm < 4; mm++) {
        int m = half * 4 + mm;
#pragma unroll
        for (int r = 0; r < 4; r++)
          smem[(mm * 16 + g * 4 + r) * 200 + colRel] = f2bf(acc[m][nn][r] + bias);
      }
    }
    __syncthreads();
    for (int u = tid; u < 384; u += 256) {
      int row = u & 63, j = u >> 6;
      int tr = row0 + half * 64 + row;
      if (tr < ntok) {
        int bw = tr / 49;
        int n = tr - bw * 49;
        short* dst = base + ((size_t)(bw * 12 + hbase + j) * 49 + n) * 32;
        const uint4* src = (const uint4*)&smem[row * 200 + j * 32];
        uint4* d4 = (uint4*)dst;
        d4[0] = src[0]; d4[1] = src[1]; d4[2] = src[2]; d4[3] = src[3];
      }
    }
  }
}

// ---------------------------------------------------------------------------
// K2: attention. One wave per (b,h). QK^T -> +bm -> softmax (register,
// shfl_xor) -> P via wave-private LDS -> PV -> O bf16 token-major [bw][n][384]
// ---------------------------------------------------------------------------
__global__ __launch_bounds__(256) void attn_kernel(
    const short* __restrict__ qws, const short* __restrict__ kws,
    const short* __restrict__ vws, short* __restrict__ ows,
    const float* __restrict__ bm, int b0, int nwmask) {
  __shared__ short Pall[4 * 64 * 72];
  const int tid = threadIdx.x;
  const int lane = tid & 63, wvi = tid >> 6;
  const int c = lane & 15, g = lane >> 4;
  const int task = blockIdx.x * 4 + wvi;   // grid = 3*nw blocks -> 12*nw tasks
  const int b = task / 12, h = task - b * 12;
  const int wm = (b0 + b) % nwmask;
  const short* qb = qws + (size_t)(b * 12 + h) * 1568;
  const short* kb = kws + (size_t)(b * 12 + h) * 1568;
  const short* vb = vws + (size_t)(b * 12 + h) * 1568;

  bf16x8 qf[4], kf[4];
#pragma unroll
  for (int m = 0; m < 4; m++) { int i = m * 16 + c; if (i > 48) i = 48; qf[m] = *(const bf16x8*)(qb + i * 32 + g * 8); }
#pragma unroll
  for (int n = 0; n < 4; n++) { int j = n * 16 + c; if (j > 48) j = 48; kf[n] = *(const bf16x8*)(kb + j * 32 + g * 8); }

  const f32x4 zero = {0.f, 0.f, 0.f, 0.f};
  f32x4 S[4][4];
#pragma unroll
  for (int m = 0; m < 4; m++)
#pragma unroll
    for (int n = 0; n < 4; n++) S[m][n] = MFMA16(qf[m], kf[n], zero);

  // + (rel-pos bias + mask), precomputed; invalid cols -> -3e38 (exp -> 0)
  const float* bmh = bm + (size_t)(wm * 12 + h) * 2401;
#pragma unroll
  for (int n = 0; n < 4; n++) {
    int j = n * 16 + c;
    if (j < 49) {
#pragma unroll
      for (int m = 0; m < 4; m++)
#pragma unroll
        for (int r = 0; r < 4; r++) {
          int i = m * 16 + g * 4 + r; if (i > 48) i = 48;
          S[m][n][r] += bmh[i * 49 + j];
        }
    } else {
#pragma unroll
      for (int m = 0; m < 4; m++)
#pragma unroll
        for (int r = 0; r < 4; r++) S[m][n][r] = -3.0e38f;
    }
  }

  // softmax per row (row's 64 cols live in the 16 lanes of group g)
  short* P = Pall + wvi * 4608;
#pragma unroll
  for (int m = 0; m < 4; m++)
#pragma unroll
    for (int r = 0; r < 4; r++) {
      float mx = fmaxf(fmaxf(S[m][0][r], S[m][1][r]), fmaxf(S[m][2][r], S[m][3][r]));
      mx = fmaxf(mx, __shfl_xor(mx, 1));
      mx = fmaxf(mx, __shfl_xor(mx, 2));
      mx = fmaxf(mx, __shfl_xor(mx, 4));
      mx = fmaxf(mx, __shfl_xor(mx, 8));
      float e0 = __expf(S[m][0][r] - mx);
      float e1 = __expf(S[m][1][r] - mx);
      float e2 = __expf(S[m][2][r] - mx);
      float e3 = __expf(S[m][3][r] - mx);
      float sm = (e0 + e1) + (e2 + e3);
      sm += __shfl_xor(sm, 1);
      sm += __shfl_xor(sm, 2);
      sm += __shfl_xor(sm, 4);
      sm += __shfl_xor(sm, 8);
      float rinv = 1.0f / sm;
      int row = m * 16 + g * 4 + r;
      P[row * 72 + c]      = f2bf(e0 * rinv);
      P[row * 72 + 16 + c] = f2bf(e1 * rinv);
      P[row * 72 + 32 + c] = f2bf(e2 * rinv);
      P[row * 72 + 48 + c] = f2bf(e3 * rinv);
    }
  // P is wave-private: same-wave LDS RAW is ordered by compiler-inserted
  // lgkmcnt waits -- no __syncthreads needed.

  f32x4 O[4][2];
#pragma unroll
  for (int m = 0; m < 4; m++) { O[m][0] = zero; O[m][1] = zero; }
#pragma unroll
  for (int kk = 0; kk < 2; kk++) {
    bf16x8 pf[4];
#pragma unroll
    for (int m = 0; m < 4; m++) pf[m] = *(const bf16x8*)&P[(m * 16 + c) * 72 + kk * 32 + g * 8];
#pragma unroll
    for (int dt = 0; dt < 2; dt++) {
      bf16x8 vf;
#pragma unroll
      for (int rr = 0; rr < 8; rr++) {
        int j = kk * 32 + g * 8 + rr; if (j > 48) j = 48;   // P[j>=49]==0
        vf[rr] = vb[j * 32 + dt * 16 + c];
      }
#pragma unroll
      for (int m = 0; m < 4; m++) O[m][dt] = MFMA16(pf[m], vf, O[m][dt]);
    }
  }
#pragma unroll
  for (int m = 0; m < 4; m++)
#pragma unroll
    for (int r = 0; r < 4; r++) {
      int i = m * 16 + g * 4 + r;
      if (i < 49) {
        size_t o = ((size_t)b * 49 + i) * 384 + h * 32;
        ows[o + c]      = f2bf(O[m][0][r]);
        ows[o + 16 + c] = f2bf(O[m][1][r]);
      }
    }
}

// ---------------------------------------------------------------------------
// K3: out = O @ Wp.T + bp ; tile 128x192 (x-blocks=2), same m97-style loop,
// direct fp32 coalesced stores
// ---------------------------------------------------------------------------
__global__ __launch_bounds__(256) void proj_gemm(
    const short* __restrict__ ows, const short* __restrict__ Wpb,
    const float* __restrict__ bpb, float* __restrict__ out,
    long tok0, int ntok) {
  __shared__ __align__(16) short smem[(128 + 192) * 64];
  short* Asl = smem;
  short* Bsl = smem + 128 * 64;
  const int tid = threadIdx.x;
  const int lane = tid & 63, wv = tid >> 6;
  const int c = lane & 15, g = lane >> 4;

  // block swizzle: 8 rows x 2 cols per 16-id group
  const int mt = gridDim.y;
  int id = blockIdx.y * 2 + blockIdx.x;
  int mt8 = mt & ~7;
  int xq, yq;
  if (id < 2 * mt8) {
    int q = id / 16, r = id - q * 16;
    yq = q * 8 + (r & 7);
    xq = r >> 3;
  } else {
    int rem = id - 2 * mt8;
    xq = rem % 2;
    yq = mt8 + rem / 2;
  }
  const int n0 = xq * 192;
  const int row0 = yq * 128;

  f32x4 acc[8][3];
  const f32x4 zero = {0.f, 0.f, 0.f, 0.f};
#pragma unroll
  for (int m = 0; m < 8; m++)
#pragma unroll
    for (int nn = 0; nn < 3; nn++) acc[m][nn] = zero;

  const int rsub = lane >> 3;
  const int chnk = ((lane & 7) ^ rsub) * 8;
  const short* aS[4];
  const short* bS[6];
#pragma unroll
  for (int i = 0; i < 4; i++) {
    int r = (wv * 4 + i) * 8 + rsub;
    int grow = row0 + r;
    if (grow >= ntok) grow = ntok - 1;
    aS[i] = ows + (size_t)grow * 384 + chnk;
  }
#pragma unroll
  for (int j = 0; j < 6; j++) {
    int r = (wv * 6 + j) * 8 + rsub;
    bS[j] = Wpb + (size_t)(n0 + r) * 384 + chnk;
  }

  for (int ks = 0; ks < 6; ks++) {
    __syncthreads();
#pragma unroll
    for (int i = 0; i < 4; i++)
      gl_lds16(aS[i] + ks * 64, Asl + (wv * 4 + i) * 512);
#pragma unroll
    for (int j = 0; j < 6; j++)
      gl_lds16(bS[j] + ks * 64, Bsl + (wv * 6 + j) * 512);
    __syncthreads();
#pragma unroll
    for (int kk = 0; kk < 2; kk++) {
      bf16x8 af[8];
#pragma unroll
      for (int m = 0; m < 8; m++) {
        int row = m * 16 + c;
        af[m] = *(const bf16x8*)&Asl[row * 64 + (((kk * 4 + g) ^ (row & 7)) * 8)];
      }
#pragma unroll
      for (int nn = 0; nn < 3; nn++) {
        int row = wv * 48 + nn * 16 + c;
        bf16x8 bfr = *(const bf16x8*)&Bsl[row * 64 + (((kk * 4 + g) ^ (row & 7)) * 8)];
#pragma unroll
        for (int m = 0; m < 8; m++) acc[m][nn] = MFMA16(af[m], bfr, acc[m][nn]);
      }
    }
  }
#pragma unroll
  for (int nn = 0; nn < 3; nn++) {
    int cg = n0 + wv * 48 + nn * 16 + c;
    float bias = bpb[cg];
#pragma unroll
    for (int m = 0; m < 8; m++)
#pragma unroll
      for (int r = 0; r < 4; r++) {
        int tr = row0 + m * 16 + g * 4 + r;
        if (tr < ntok) out[((size_t)(tok0 + tr)) * 384 + cg] = acc[m][nn][r] + bias;
      }
  }
}

// ---------------------------------------------------------------------------
extern "C" void kernel_launch(void* const* d_in, const int* in_sizes, int n_in,
                              void* d_out, int out_size, void* d_ws, size_t ws_size,
                              hipStream_t stream) {
  const float* x    = (const float*)d_in[0];
  const float* mask = (const float*)d_in[1];
  const float* Wq = (const float*)d_in[2];
  const float* bq = (const float*)d_in[3];
  const float* Wk = (const float*)d_in[4];
  const float* bk = (const float*)d_in[5];
  const float* Wv = (const float*)d_in[6];
  const float* bv = (const float*)d_in[7];
  const float* Wp = (const float*)d_in[8];
  const float* bp = (const float*)d_in[9];
  const float* table = (const float*)d_in[10];
  float* out = (float*)d_out;

  const int Btot = in_sizes[0] / (49 * 384);   // 2048
  const int NWm  = in_sizes[1] / (49 * 49);    // 64

  char* ws = (char*)d_ws;
  short* Wqkv = (short*)ws;                     // 1152*384 bf16
  short* Wpb  = Wqkv + 1152 * 384;              // 384*384 bf16
  float* bqkv = (float*)(Wpb + 384 * 384);      // 1152 f32
  float* bpb  = bqkv + 1152;                    // 384 f32
  float* bmp  = bpb + 384;                      // NWm*12*2401 f32
  size_t fixedB = (size_t)(1152 * 384 + 384 * 384) * 2 + (1152 + 384) * 4
                + (size_t)NWm * 12 * 2401 * 4;
  char* dyn = ws + ((fixedB + 255) & ~(size_t)255);
  size_t used = (size_t)(dyn - ws);
  size_t avail = (ws_size > used + 4096) ? (ws_size - used - 4096) : 0;
  const size_t perw = (size_t)5 * 18816 * 2;    // xb,q,k,v,O bf16 per window
  long nwc = (long)(avail / perw);
  if (nwc > Btot) nwc = Btot;
  if (nwc >= 64) nwc &= ~63L;
  if (nwc < 1) nwc = 1;
  short* xbw = (short*)dyn;
  short* qws = xbw + (size_t)nwc * 18816;
  short* kws = qws + (size_t)nwc * 18816;
  short* vws = kws + (size_t)nwc * 18816;
  short* ows = vws + (size_t)nwc * 18816;

  prep_w<<<dim3(1728), dim3(256), 0, stream>>>(Wq, bq, Wk, bk, Wv, bv, Wp, bp,
                                               Wqkv, Wpb, bqkv, bpb);
  prep_bm<<<dim3(NWm * 12), dim3(256), 0, stream>>>(table, mask, bmp, NWm);

  for (long b0 = 0; b0 < Btot; b0 += nwc) {
    int nw = (int)((Btot - b0 < nwc) ? (Btot - b0) : nwc);
    int ntok = nw * 49;
    long tok0 = b0 * 49;
    int n8 = ntok * 48;  // ntok*384/8
    prep_x<<<dim3((n8 + 255) / 256), dim3(256), 0, stream>>>(x + tok0 * 384, xbw, n8);
    int mt = (ntok + 127) / 128;
    qkv_gemm<<<dim3(6, mt), dim3(256), 0, stream>>>(xbw, Wqkv, bqkv, qws, kws, vws, ntok);
    attn_kernel<<<dim3(3 * nw), dim3(256), 0, stream>>>(qws, kws, vws, ows, bmp,
                                                        (int)b0, NWm);
    proj_gemm<<<dim3(2, mt), dim3(256), 0, stream>>>(ows, Wpb, bpb, out, tok0, ntok);
  }
}

// Round 2
// 623.961 us; speedup vs baseline: 1.1216x; 1.0547x over previous
//
#include <hip/hip_runtime.h>
#include <stdint.h>

using bf16x8 = __attribute__((ext_vector_type(8))) short;
using f32x4  = __attribute__((ext_vector_type(4))) float;

__device__ __forceinline__ short f2bf(float f) {
  uint32_t u = __float_as_uint(f);
  u += 0x7fff + ((u >> 16) & 1u);
  return (short)(u >> 16);
}

#define MFMA16(a, b, c) __builtin_amdgcn_mfma_f32_16x16x32_bf16((a), (b), (c), 0, 0, 0)

// async global->LDS, 16B per lane; LDS dest is wave-uniform base + lane*16
__device__ __forceinline__ void gl_lds16(const short* g, short* l) {
  __builtin_amdgcn_global_load_lds(
      (const __attribute__((address_space(1))) void*)g,
      (__attribute__((address_space(3))) void*)l, 16, 0, 0);
}

// ---------------------------------------------------------------------------
// prep_w: pack Wq*scale|Wk|Wv -> bf16 [1152][384], Wp -> bf16, biases fp32
// ---------------------------------------------------------------------------
__global__ void prep_w(const float* __restrict__ Wq, const float* __restrict__ bq,
                       const float* __restrict__ Wk, const float* __restrict__ bk,
                       const float* __restrict__ Wv, const float* __restrict__ bv,
                       const float* __restrict__ Wp, const float* __restrict__ bp,
                       short* __restrict__ Wqkv, short* __restrict__ Wpb,
                       float* __restrict__ bqkv, float* __restrict__ bpb) {
  int i = blockIdx.x * 256 + threadIdx.x;
  const float scale = 0.17677669529663687f;  // 32^-0.5, folded into q
  if (i < 1152 * 384) {
    int r = i / 384, k = i - r * 384;
    float v;
    if (r < 384)      v = Wq[r * 384 + k] * scale;
    else if (r < 768) v = Wk[(r - 384) * 384 + k];
    else              v = Wv[(r - 768) * 384 + k];
    Wqkv[i] = f2bf(v);
  }
  if (i < 384 * 384) Wpb[i] = f2bf(Wp[i]);
  if (i < 1152) bqkv[i] = (i < 384) ? bq[i] * scale : ((i < 768) ? bk[i - 384] : bv[i - 768]);
  if (i < 384) bpb[i] = bp[i];
}

// ---------------------------------------------------------------------------
// prep_bm: bm[wm][h][i][j] = table[relidx(i,j)][h] + mask[wm][i][j]  (fp32)
// ---------------------------------------------------------------------------
__global__ void prep_bm(const float* __restrict__ table, const float* __restrict__ mask,
                        float* __restrict__ bm, int nwmask) {
  int wm = blockIdx.x / 12, h = blockIdx.x - wm * 12;
  const float* mrow = mask + (size_t)wm * 2401;
  float* dst = bm + (size_t)blockIdx.x * 2401;
  for (int e = threadIdx.x; e < 2401; e += 256) {
    int i = e / 49, j = e - i * 49;
    int id = i / 7, ir = i - id * 7;
    int jd = j / 7, jr = j - jd * 7;
    int idx = (id - jd + 6) * 13 + (ir - jr + 6);
    dst[e] = table[idx * 12 + h] + mrow[e];
  }
}

// ---------------------------------------------------------------------------
// prep_x: fp32 -> bf16 conversion of a chunk of x (8 elements / thread)
// ---------------------------------------------------------------------------
__global__ void prep_x(const float* __restrict__ x, short* __restrict__ xb, int n8) {
  int u = blockIdx.x * 256 + threadIdx.x;
  if (u < n8) {
    int e = u * 8;
    float4 f0 = *(const float4*)(x + e);
    float4 f1 = *(const float4*)(x + e + 4);
    bf16x8 cv;
    cv[0] = f2bf(f0.x); cv[1] = f2bf(f0.y); cv[2] = f2bf(f0.z); cv[3] = f2bf(f0.w);
    cv[4] = f2bf(f1.x); cv[5] = f2bf(f1.y); cv[6] = f2bf(f1.z); cv[7] = f2bf(f1.w);
    *(bf16x8*)(xb + e) = cv;
  }
}

// ---------------------------------------------------------------------------
// K1: qkv = xb @ Wqkv.T + bqkv ; writes q,k,v bf16 in [bw][h][n][32] layout
// tile 128(M) x 192(N), 4 waves, BK=64, K=384 (6 iters)
// 2-phase double-buffered pipeline (T3 minimum): STAGE(next) issued BEFORE
// compute(cur); single vmcnt(0)+barrier per K-iter (inside __syncthreads).
// global_load_lds width-16; linear LDS dest + XOR-swizzled source; ds_read
// applies the same XOR -> conflict-free (measured 0 last round).
// Block swizzle: 48-id groups share id%8 (XCD) and one M-row -> A-tile L2 hits.
// ---------------------------------------------------------------------------
__global__ __launch_bounds__(256) void qkv_gemm(
    const short* __restrict__ xb, const short* __restrict__ Wqkv,
    const float* __restrict__ bqkv,
    short* __restrict__ qws, short* __restrict__ kws, short* __restrict__ vws,
    int ntok) {
  // two buffers: each buf = As[128][64] | Bs[192][64] = 320*64 shorts
  __shared__ __align__(16) short smem[2 * 320 * 64];   // 80 KiB -> 2 blocks/CU
  const int tid = threadIdx.x;
  const int lane = tid & 63, wv = tid >> 6;
  const int c = lane & 15, g = lane >> 4;

  // ---- block swizzle: id -> (xq, yq), 8 rows x 6 cols per 48-id group ----
  const int mt = gridDim.y;
  int id = blockIdx.y * 6 + blockIdx.x;
  int mt8 = mt & ~7;
  int xq, yq;
  if (id < 6 * mt8) {
    int q = id / 48, r = id - q * 48;
    yq = q * 8 + (r & 7);
    xq = r >> 3;
  } else {
    int rem = id - 6 * mt8;
    xq = rem % 6;
    yq = mt8 + rem / 6;
  }
  const int n0 = xq * 192;
  const int row0 = yq * 128;

  f32x4 acc[8][3];
  const f32x4 zero = {0.f, 0.f, 0.f, 0.f};
#pragma unroll
  for (int m = 0; m < 8; m++)
#pragma unroll
    for (int nn = 0; nn < 3; nn++) acc[m][nn] = zero;

  // per-lane source swizzle: lane covers (row r0+(lane>>3), chunk lane&7);
  // logical chunk = (lane&7) ^ (r&7) with r&7 == lane>>3
  const int rsub = lane >> 3;
  const int chnk = ((lane & 7) ^ rsub) * 8;  // short offset within a 64-elt row
  const short* aS[4];
  const short* bS[6];
#pragma unroll
  for (int i = 0; i < 4; i++) {
    int r = (wv * 4 + i) * 8 + rsub;
    int grow = row0 + r;
    if (grow >= ntok) grow = ntok - 1;
    aS[i] = xb + (size_t)grow * 384 + chnk;
  }
#pragma unroll
  for (int j = 0; j < 6; j++) {
    int r = (wv * 6 + j) * 8 + rsub;
    bS[j] = Wqkv + (size_t)(n0 + r) * 384 + chnk;
  }

  auto stage = [&](int buf, int ks) {
    short* Asl = smem + buf * (320 * 64);
    short* Bsl = Asl + 128 * 64;
#pragma unroll
    for (int i = 0; i < 4; i++)
      gl_lds16(aS[i] + ks * 64, Asl + (wv * 4 + i) * 512);
#pragma unroll
    for (int j = 0; j < 6; j++)
      gl_lds16(bS[j] + ks * 64, Bsl + (wv * 6 + j) * 512);
  };

  stage(0, 0);
  __syncthreads();                 // tile 0 resident
  for (int ks = 0; ks < 6; ks++) {
    const int cur = ks & 1;
    if (ks < 5) stage(cur ^ 1, ks + 1);   // prefetch next tile: latency hides under MFMA
    const short* Asl = smem + cur * (320 * 64);
    const short* Bsl = Asl + 128 * 64;
#pragma unroll
    for (int kk = 0; kk < 2; kk++) {
      bf16x8 af[8];
#pragma unroll
      for (int m = 0; m < 8; m++) {
        int row = m * 16 + c;
        af[m] = *(const bf16x8*)&Asl[row * 64 + (((kk * 4 + g) ^ (row & 7)) * 8)];
      }
#pragma unroll
      for (int nn = 0; nn < 3; nn++) {
        int row = wv * 48 + nn * 16 + c;
        bf16x8 bfr = *(const bf16x8*)&Bsl[row * 64 + (((kk * 4 + g) ^ (row & 7)) * 8)];
#pragma unroll
        for (int m = 0; m < 8; m++) acc[m][nn] = MFMA16(af[m], bfr, acc[m][nn]);
      }
    }
    __syncthreads();               // drains vmcnt(0): next tile ready, cur reads done
  }

  // epilogue in two 64-row halves through LDS, scatter to [bw][h][n][32]
  const int s = n0 / 384;
  short* base = (s == 0) ? qws : ((s == 1) ? kws : vws);
  const int hbase = (n0 - s * 384) >> 5;
#pragma unroll
  for (int half = 0; half < 2; half++) {
    __syncthreads();
#pragma unroll
    for (int nn = 0; nn < 3; nn++) {
      int colRel = wv * 48 + nn * 16 + c;
      float bias = bqkv[n0 + colRel];
#pragma unroll
      for (int mm = 0; mm < 4; mm++) {
        int m = half * 4 + mm;
#pragma unroll
        for (int r = 0; r < 4; r++)
          smem[(mm * 16 + g * 4 + r) * 200 + colRel] = f2bf(acc[m][nn][r] + bias);
      }
    }
    __syncthreads();
    for (int u = tid; u < 384; u += 256) {
      int row = u & 63, j = u >> 6;
      int tr = row0 + half * 64 + row;
      if (tr < ntok) {
        int bw = tr / 49;
        int n = tr - bw * 49;
        short* dst = base + ((size_t)(bw * 12 + hbase + j) * 49 + n) * 32;
        const uint4* src = (const uint4*)&smem[row * 200 + j * 32];
        uint4* d4 = (uint4*)dst;
        d4[0] = src[0]; d4[1] = src[1]; d4[2] = src[2]; d4[3] = src[3];
      }
    }
  }
}

// ---------------------------------------------------------------------------
// K2: attention. One wave per (b,h). QK^T -> +bm -> softmax (register,
// shfl_xor) -> P via wave-private LDS -> PV -> O bf16 token-major [bw][n][384]
// ---------------------------------------------------------------------------
__global__ __launch_bounds__(256) void attn_kernel(
    const short* __restrict__ qws, const short* __restrict__ kws,
    const short* __restrict__ vws, short* __restrict__ ows,
    const float* __restrict__ bm, int b0, int nwmask) {
  __shared__ short Pall[4 * 64 * 72];
  const int tid = threadIdx.x;
  const int lane = tid & 63, wvi = tid >> 6;
  const int c = lane & 15, g = lane >> 4;
  const int task = blockIdx.x * 4 + wvi;   // grid = 3*nw blocks -> 12*nw tasks
  const int b = task / 12, h = task - b * 12;
  const int wm = (b0 + b) % nwmask;
  const short* qb = qws + (size_t)(b * 12 + h) * 1568;
  const short* kb = kws + (size_t)(b * 12 + h) * 1568;
  const short* vb = vws + (size_t)(b * 12 + h) * 1568;

  bf16x8 qf[4], kf[4];
#pragma unroll
  for (int m = 0; m < 4; m++) { int i = m * 16 + c; if (i > 48) i = 48; qf[m] = *(const bf16x8*)(qb + i * 32 + g * 8); }
#pragma unroll
  for (int n = 0; n < 4; n++) { int j = n * 16 + c; if (j > 48) j = 48; kf[n] = *(const bf16x8*)(kb + j * 32 + g * 8); }

  const f32x4 zero = {0.f, 0.f, 0.f, 0.f};
  f32x4 S[4][4];
#pragma unroll
  for (int m = 0; m < 4; m++)
#pragma unroll
    for (int n = 0; n < 4; n++) S[m][n] = MFMA16(qf[m], kf[n], zero);

  // + (rel-pos bias + mask), precomputed; invalid cols -> -3e38 (exp -> 0)
  const float* bmh = bm + (size_t)(wm * 12 + h) * 2401;
#pragma unroll
  for (int n = 0; n < 4; n++) {
    int j = n * 16 + c;
    if (j < 49) {
#pragma unroll
      for (int m = 0; m < 4; m++)
#pragma unroll
        for (int r = 0; r < 4; r++) {
          int i = m * 16 + g * 4 + r; if (i > 48) i = 48;
          S[m][n][r] += bmh[i * 49 + j];
        }
    } else {
#pragma unroll
      for (int m = 0; m < 4; m++)
#pragma unroll
        for (int r = 0; r < 4; r++) S[m][n][r] = -3.0e38f;
    }
  }

  // softmax per row (row's 64 cols live in the 16 lanes of group g)
  short* P = Pall + wvi * 4608;
#pragma unroll
  for (int m = 0; m < 4; m++)
#pragma unroll
    for (int r = 0; r < 4; r++) {
      float mx = fmaxf(fmaxf(S[m][0][r], S[m][1][r]), fmaxf(S[m][2][r], S[m][3][r]));
      mx = fmaxf(mx, __shfl_xor(mx, 1));
      mx = fmaxf(mx, __shfl_xor(mx, 2));
      mx = fmaxf(mx, __shfl_xor(mx, 4));
      mx = fmaxf(mx, __shfl_xor(mx, 8));
      float e0 = __expf(S[m][0][r] - mx);
      float e1 = __expf(S[m][1][r] - mx);
      float e2 = __expf(S[m][2][r] - mx);
      float e3 = __expf(S[m][3][r] - mx);
      float sm = (e0 + e1) + (e2 + e3);
      sm += __shfl_xor(sm, 1);
      sm += __shfl_xor(sm, 2);
      sm += __shfl_xor(sm, 4);
      sm += __shfl_xor(sm, 8);
      float rinv = 1.0f / sm;
      int row = m * 16 + g * 4 + r;
      P[row * 72 + c]      = f2bf(e0 * rinv);
      P[row * 72 + 16 + c] = f2bf(e1 * rinv);
      P[row * 72 + 32 + c] = f2bf(e2 * rinv);
      P[row * 72 + 48 + c] = f2bf(e3 * rinv);
    }
  // P is wave-private: same-wave LDS RAW is ordered by compiler-inserted
  // lgkmcnt waits -- no __syncthreads needed.

  f32x4 O[4][2];
#pragma unroll
  for (int m = 0; m < 4; m++) { O[m][0] = zero; O[m][1] = zero; }
#pragma unroll
  for (int kk = 0; kk < 2; kk++) {
    bf16x8 pf[4];
#pragma unroll
    for (int m = 0; m < 4; m++) pf[m] = *(const bf16x8*)&P[(m * 16 + c) * 72 + kk * 32 + g * 8];
#pragma unroll
    for (int dt = 0; dt < 2; dt++) {
      bf16x8 vf;
#pragma unroll
      for (int rr = 0; rr < 8; rr++) {
        int j = kk * 32 + g * 8 + rr; if (j > 48) j = 48;   // P[j>=49]==0
        vf[rr] = vb[j * 32 + dt * 16 + c];
      }
#pragma unroll
      for (int m = 0; m < 4; m++) O[m][dt] = MFMA16(pf[m], vf, O[m][dt]);
    }
  }
#pragma unroll
  for (int m = 0; m < 4; m++)
#pragma unroll
    for (int r = 0; r < 4; r++) {
      int i = m * 16 + g * 4 + r;
      if (i < 49) {
        size_t o = ((size_t)b * 49 + i) * 384 + h * 32;
        ows[o + c]      = f2bf(O[m][0][r]);
        ows[o + 16 + c] = f2bf(O[m][1][r]);
      }
    }
}

// ---------------------------------------------------------------------------
// K3: out = O @ Wp.T + bp ; tile 128x192 (x-blocks=2), 2-phase double-buffered
// pipeline like K1; direct fp32 coalesced stores
// ---------------------------------------------------------------------------
__global__ __launch_bounds__(256) void proj_gemm(
    const short* __restrict__ ows, const short* __restrict__ Wpb,
    const float* __restrict__ bpb, float* __restrict__ out,
    long tok0, int ntok) {
  __shared__ __align__(16) short smem[2 * 320 * 64];
  const int tid = threadIdx.x;
  const int lane = tid & 63, wv = tid >> 6;
  const int c = lane & 15, g = lane >> 4;

  // block swizzle: 8 rows x 2 cols per 16-id group
  const int mt = gridDim.y;
  int id = blockIdx.y * 2 + blockIdx.x;
  int mt8 = mt & ~7;
  int xq, yq;
  if (id < 2 * mt8) {
    int q = id / 16, r = id - q * 16;
    yq = q * 8 + (r & 7);
    xq = r >> 3;
  } else {
    int rem = id - 2 * mt8;
    xq = rem % 2;
    yq = mt8 + rem / 2;
  }
  const int n0 = xq * 192;
  const int row0 = yq * 128;

  f32x4 acc[8][3];
  const f32x4 zero = {0.f, 0.f, 0.f, 0.f};
#pragma unroll
  for (int m = 0; m < 8; m++)
#pragma unroll
    for (int nn = 0; nn < 3; nn++) acc[m][nn] = zero;

  const int rsub = lane >> 3;
  const int chnk = ((lane & 7) ^ rsub) * 8;
  const short* aS[4];
  const short* bS[6];
#pragma unroll
  for (int i = 0; i < 4; i++) {
    int r = (wv * 4 + i) * 8 + rsub;
    int grow = row0 + r;
    if (grow >= ntok) grow = ntok - 1;
    aS[i] = ows + (size_t)grow * 384 + chnk;
  }
#pragma unroll
  for (int j = 0; j < 6; j++) {
    int r = (wv * 6 + j) * 8 + rsub;
    bS[j] = Wpb + (size_t)(n0 + r) * 384 + chnk;
  }

  auto stage = [&](int buf, int ks) {
    short* Asl = smem + buf * (320 * 64);
    short* Bsl = Asl + 128 * 64;
#pragma unroll
    for (int i = 0; i < 4; i++)
      gl_lds16(aS[i] + ks * 64, Asl + (wv * 4 + i) * 512);
#pragma unroll
    for (int j = 0; j < 6; j++)
      gl_lds16(bS[j] + ks * 64, Bsl + (wv * 6 + j) * 512);
  };

  stage(0, 0);
  __syncthreads();
  for (int ks = 0; ks < 6; ks++) {
    const int cur = ks & 1;
    if (ks < 5) stage(cur ^ 1, ks + 1);
    const short* Asl = smem + cur * (320 * 64);
    const short* Bsl = Asl + 128 * 64;
#pragma unroll
    for (int kk = 0; kk < 2; kk++) {
      bf16x8 af[8];
#pragma unroll
      for (int m = 0; m < 8; m++) {
        int row = m * 16 + c;
        af[m] = *(const bf16x8*)&Asl[row * 64 + (((kk * 4 + g) ^ (row & 7)) * 8)];
      }
#pragma unroll
      for (int nn = 0; nn < 3; nn++) {
        int row = wv * 48 + nn * 16 + c;
        bf16x8 bfr = *(const bf16x8*)&Bsl[row * 64 + (((kk * 4 + g) ^ (row & 7)) * 8)];
#pragma unroll
        for (int m = 0; m < 8; m++) acc[m][nn] = MFMA16(af[m], bfr, acc[m][nn]);
      }
    }
    __syncthreads();
  }
#pragma unroll
  for (int nn = 0; nn < 3; nn++) {
    int cg = n0 + wv * 48 + nn * 16 + c;
    float bias = bpb[cg];
#pragma unroll
    for (int m = 0; m < 8; m++)
#pragma unroll
      for (int r = 0; r < 4; r++) {
        int tr = row0 + m * 16 + g * 4 + r;
        if (tr < ntok) out[((size_t)(tok0 + tr)) * 384 + cg] = acc[m][nn][r] + bias;
      }
  }
}

// ---------------------------------------------------------------------------
extern "C" void kernel_launch(void* const* d_in, const int* in_sizes, int n_in,
                              void* d_out, int out_size, void* d_ws, size_t ws_size,
                              hipStream_t stream) {
  const float* x    = (const float*)d_in[0];
  const float* mask = (const float*)d_in[1];
  const float* Wq = (const float*)d_in[2];
  const float* bq = (const float*)d_in[3];
  const float* Wk = (const float*)d_in[4];
  const float* bk = (const float*)d_in[5];
  const float* Wv = (const float*)d_in[6];
  const float* bv = (const float*)d_in[7];
  const float* Wp = (const float*)d_in[8];
  const float* bp = (const float*)d_in[9];
  const float* table = (const float*)d_in[10];
  float* out = (float*)d_out;

  const int Btot = in_sizes[0] / (49 * 384);   // 2048
  const int NWm  = in_sizes[1] / (49 * 49);    // 64

  char* ws = (char*)d_ws;
  short* Wqkv = (short*)ws;                     // 1152*384 bf16
  short* Wpb  = Wqkv + 1152 * 384;              // 384*384 bf16
  float* bqkv = (float*)(Wpb + 384 * 384);      // 1152 f32
  float* bpb  = bqkv + 1152;                    // 384 f32
  float* bmp  = bpb + 384;                      // NWm*12*2401 f32
  size_t fixedB = (size_t)(1152 * 384 + 384 * 384) * 2 + (1152 + 384) * 4
                + (size_t)NWm * 12 * 2401 * 4;
  char* dyn = ws + ((fixedB + 255) & ~(size_t)255);
  size_t used = (size_t)(dyn - ws);
  size_t avail = (ws_size > used + 4096) ? (ws_size - used - 4096) : 0;
  const size_t perw = (size_t)5 * 18816 * 2;    // xb,q,k,v,O bf16 per window
  long nwc = (long)(avail / perw);
  if (nwc > Btot) nwc = Btot;
  if (nwc >= 64) nwc &= ~63L;
  if (nwc < 1) nwc = 1;
  short* xbw = (short*)dyn;
  short* qws = xbw + (size_t)nwc * 18816;
  short* kws = qws + (size_t)nwc * 18816;
  short* vws = kws + (size_t)nwc * 18816;
  short* ows = vws + (size_t)nwc * 18816;

  prep_w<<<dim3(1728), dim3(256), 0, stream>>>(Wq, bq, Wk, bk, Wv, bv, Wp, bp,
                                               Wqkv, Wpb, bqkv, bpb);
  prep_bm<<<dim3(NWm * 12), dim3(256), 0, stream>>>(table, mask, bmp, NWm);

  for (long b0 = 0; b0 < Btot; b0 += nwc) {
    int nw = (int)((Btot - b0 < nwc) ? (Btot - b0) : nwc);
    int ntok = nw * 49;
    long tok0 = b0 * 49;
    int n8 = ntok * 48;  // ntok*384/8
    prep_x<<<dim3((n8 + 255) / 256), dim3(256), 0, stream>>>(x + tok0 * 384, xbw, n8);
    int mt = (ntok + 127) / 128;
    qkv_gemm<<<dim3(6, mt), dim3(256), 0, stream>>>(xbw, Wqkv, bqkv, qws, kws, vws, ntok);
    attn_kernel<<<dim3(3 * nw), dim3(256), 0, stream>>>(qws, kws, vws, ows, bmp,
                                                        (int)b0, NWm);
    proj_gemm<<<dim3(2, mt), dim3(256), 0, stream>>>(ows, Wpb, bpb, out, tok0, ntok);
  }
}